// Round 5
// baseline (941.712 us; speedup 1.0000x reference)
//
#include <hip/hip_runtime.h>
#include <stdint.h>

namespace {
constexpr int B_ = 16, D_ = 64, N_ = 128, L_ = 256;
constexpr int PE1 = 32, F1 = L_ + PE1;     // 288
constexpr int D1 = 64;
constexpr int ND1 = N_ * D1;               // 8192
constexpr int PE2 = 16, F2 = ND1 + PE2;    // 8208
constexpr int D2 = 128;
constexpr int NC_ = 2;
constexpr int TOPK1 = 8, TOPK2 = 4;
constexpr int NP = B_ * D_;                // 1024 (b,d) pairs
constexpr int KS2 = 32, S2CH = 257;        // ceil(8208/32)
constexpr int KSY = 32, YCH = 257;
}

__device__ __forceinline__ int ctz32(unsigned int m) { return __builtin_ctz(m); }
__device__ __forceinline__ int ctz64(uint64_t m) { return __builtin_ctzll(m); }
__device__ __forceinline__ int pop64(uint64_t m) { return __builtin_popcountll(m); }

// ---------------------------------------------------------------- stage 1
// Fused: S = X@X^T kept in LDS -> top-8 rows -> symmetrized bitmask + dinv.
// LDS: union{ Xt[32][132] staging | S[128][128] } = 64 KiB (+2 KiB bits).
__global__ __launch_bounds__(256) void k_S_topk(const float* __restrict__ x,
                                                uint32_t* __restrict__ bits1,
                                                float* __restrict__ dinv1) {
  int p = blockIdx.x;
  const float* X = x + (size_t)p * N_ * L_;
  __shared__ float smem[N_ * N_];          // 64 KiB union
  __shared__ unsigned int bits[N_][4];
  int t = threadIdx.x, tx = t & 15, ty = t >> 4;
  float acc[8][8] = {};
  for (int k0 = 0; k0 < L_; k0 += 32) {
    for (int i = t; i < N_ * 32; i += 256) {
      int kk = i & 31, n = i >> 5;
      smem[kk * 132 + n] = X[n * L_ + k0 + kk];   // Xt[kk][n], 132 pad: 16B rows
    }
    __syncthreads();
    for (int kk = 0; kk < 32; ++kk) {
      float a[8], bb[8];
      #pragma unroll
      for (int r = 0; r < 8; ++r) a[r] = smem[kk * 132 + ty * 8 + r];
      #pragma unroll
      for (int c = 0; c < 8; ++c) bb[c] = smem[kk * 132 + tx * 8 + c];
      #pragma unroll
      for (int r = 0; r < 8; ++r)
        #pragma unroll
        for (int c = 0; c < 8; ++c) acc[r][c] += a[r] * bb[c];
    }
    __syncthreads();
  }
  // staging reads done (trailing sync) -> alias smem as S[128][128]
  for (int r = 0; r < 8; ++r)
    #pragma unroll
    for (int c = 0; c < 8; ++c)
      smem[(ty * 8 + r) * N_ + tx * 8 + c] = acc[r][c];
  for (int i = t; i < N_ * 4; i += 256) ((unsigned int*)bits)[i] = 0u;
  __syncthreads();
  int lane = t & 63, wave = t >> 6;
  for (int r = wave; r < N_; r += 4) {
    float v0 = smem[r * N_ + lane];
    float v1 = smem[r * N_ + lane + 64];
    if (lane == r) v0 = -INFINITY;
    if (lane + 64 == r) v1 = -INFINITY;
    for (int it = 0; it < TOPK1; ++it) {     // jax tie-break: larger v, smaller idx
      float v; int idx;
      if (v0 >= v1) { v = v0; idx = lane; } else { v = v1; idx = lane + 64; }
      for (int off = 32; off; off >>= 1) {
        float ov = __shfl_xor(v, off);
        int   oi = __shfl_xor(idx, off);
        if (ov > v || (ov == v && oi < idx)) { v = ov; idx = oi; }
      }
      if (idx == lane) v0 = -INFINITY;
      else if (idx == lane + 64) v1 = -INFINITY;
      if (lane == 0) {
        atomicOr(&bits[r][idx >> 5], 1u << (idx & 31));
        atomicOr(&bits[idx][r >> 5], 1u << (r & 31));  // symmetrize
      }
    }
  }
  __syncthreads();
  if (t < N_) {
    int deg = 1;
    for (int w = 0; w < 4; ++w) deg += __popc(bits[t][w]);
    dinv1[(size_t)p * N_ + t] = rsqrtf((float)deg);
  }
  for (int i = t; i < N_ * 4; i += 256)
    bits1[(size_t)p * 512 + i] = ((unsigned int*)bits)[i];
}

// Fused: G = concat(x,pe)@W_time[d] kept in LDS (pre-scaled by dinv) ->
// sparse GCN aggregation -> h.  LDS union{Ft[32][132]+Wt[32][64] | Gs[128][64]}.
__global__ __launch_bounds__(256) void k_G_h(const float* __restrict__ x,
                                             const float* __restrict__ pe_inter,
                                             const float* __restrict__ W_time,
                                             const uint32_t* __restrict__ bits1,
                                             const float* __restrict__ dinv1,
                                             const float* __restrict__ b_time,
                                             float* __restrict__ h) {
  int p = blockIdx.x, d = p & 63;
  const float* X = x + (size_t)p * N_ * L_;
  const float* W = W_time + (size_t)d * F1 * D1;
  __shared__ float smem[N_ * D1];          // 32 KiB union
  __shared__ unsigned int bs[N_][4];
  __shared__ float dvs[N_];
  float* Ft = smem;                        // [32][132]
  float* Wt = smem + 4224;                 // [32][64]
  int t = threadIdx.x, tx = t & 15, ty = t >> 4;
  if (t < N_) dvs[t] = dinv1[(size_t)p * N_ + t];
  for (int i = t; i < N_ * 4; i += 256)
    ((unsigned int*)bs)[i] = bits1[(size_t)p * 512 + i];
  float acc[8][4] = {};
  for (int k0 = 0; k0 < F1; k0 += 32) {
    for (int i = t; i < N_ * 32; i += 256) {
      int kk = i & 31, n = i >> 5, k = k0 + kk;
      Ft[kk * 132 + n] = (k < L_) ? X[n * L_ + k] : pe_inter[n * PE1 + (k - L_)];
    }
    for (int i = t; i < 32 * D1; i += 256) {
      int f = i & 63, kk = i >> 6;
      Wt[kk * 64 + f] = W[(k0 + kk) * D1 + f];
    }
    __syncthreads();
    for (int kk = 0; kk < 32; ++kk) {
      float a[8], bb[4];
      #pragma unroll
      for (int r = 0; r < 8; ++r) a[r] = Ft[kk * 132 + ty * 8 + r];
      #pragma unroll
      for (int c = 0; c < 4; ++c) bb[c] = Wt[kk * 64 + tx * 4 + c];
      #pragma unroll
      for (int r = 0; r < 8; ++r)
        #pragma unroll
        for (int c = 0; c < 4; ++c) acc[r][c] += a[r] * bb[c];
    }
    __syncthreads();
  }
  // alias smem as Gs[128][64], pre-scaled by dinv (trailing sync passed)
  for (int r = 0; r < 8; ++r) {
    float dv = dvs[ty * 8 + r];
    #pragma unroll
    for (int c = 0; c < 4; ++c)
      smem[(ty * 8 + r) * D1 + tx * 4 + c] = acc[r][c] * dv;
  }
  __syncthreads();
  int f = t & 63, wg = t >> 6;
  const float* bt = b_time + d * D1;
  float* hp = h + (size_t)p * N_ * D1;
  for (int row = wg; row < N_; row += 4) {       // row uniform per wave
    float a = smem[row * D1 + f];                // self-loop term
    #pragma unroll
    for (int w = 0; w < 4; ++w) {
      unsigned int m = bs[row][w];
      while (m) { int j = (w << 5) + ctz32(m); m &= m - 1; a += smem[j * D1 + f]; }
    }
    hp[row * D1 + f] = dvs[row] * a + bt[f];
  }
}

// ---------------------------------------------------------------- stage 2
// S2 partials: per (b, kchunk): [64][64] partial of feat2@feat2^T
__global__ __launch_bounds__(256) void k_S2p(const float* __restrict__ h,
                                             const float* __restrict__ pe_dim,
                                             float* __restrict__ S2p) {
  int b = blockIdx.x, s = blockIdx.y;
  int k0 = s * S2CH, kend = k0 + S2CH; if (kend > F2) kend = F2;
  __shared__ float Ft[D_][33];
  int t = threadIdx.x, tx = t & 15, ty = t >> 4;
  float acc[4][4] = {};
  for (int kt = k0; kt < kend; kt += 32) {
    for (int i = t; i < D_ * 32; i += 256) {
      int kk = i & 31, dd = i >> 5, k = kt + kk;
      float v = 0.f;
      if (k < kend)
        v = (k < ND1) ? h[(((size_t)b * D_ + dd) * N_ + (k >> 6)) * D1 + (k & 63)]
                      : pe_dim[dd * PE2 + (k - ND1)];
      Ft[dd][kk] = v;
    }
    __syncthreads();
    for (int kk = 0; kk < 32; ++kk) {
      float a[4], bb[4];
      #pragma unroll
      for (int r = 0; r < 4; ++r) a[r] = Ft[ty * 4 + r][kk];
      #pragma unroll
      for (int c = 0; c < 4; ++c) bb[c] = Ft[tx * 4 + c][kk];
      #pragma unroll
      for (int r = 0; r < 4; ++r)
        #pragma unroll
        for (int c = 0; c < 4; ++c) acc[r][c] += a[r] * bb[c];
    }
    __syncthreads();
  }
  float* out = S2p + (size_t)(b * KS2 + s) * D_ * D_;
  for (int r = 0; r < 4; ++r)
    for (int c = 0; c < 4; ++c)
      out[(ty * 4 + r) * D_ + tx * 4 + c] = acc[r][c];
}

// reduce S2 partials -> top-4 -> symmetrize -> 2-hop reach -> dim dinv
__global__ __launch_bounds__(256) void k_dimgraph(const float* __restrict__ S2p,
                                                  uint64_t* __restrict__ Adb,
                                                  uint64_t* __restrict__ Rb,
                                                  float* __restrict__ dinvA) {
  int b = blockIdx.x;
  __shared__ float S2s[D_][D_ + 1];
  __shared__ unsigned int bits[D_][2];
  __shared__ uint64_t Ads[D_];
  int t = threadIdx.x, lane = t & 63, wave = t >> 6;
  for (int i = t; i < D_ * D_; i += 256) {
    float acc = 0.f;
    for (int s = 0; s < KS2; ++s) acc += S2p[(size_t)(b * KS2 + s) * D_ * D_ + i];
    S2s[i >> 6][i & 63] = acc;
  }
  if (t < D_ * 2) ((unsigned int*)bits)[t] = 0u;
  __syncthreads();
  for (int r = wave; r < D_; r += 4) {
    float v = S2s[r][lane];
    if (lane == r) v = -INFINITY;
    for (int it = 0; it < TOPK2; ++it) {
      float bv = v; int idx = lane;
      for (int off = 32; off; off >>= 1) {
        float ov = __shfl_xor(bv, off);
        int   oi = __shfl_xor(idx, off);
        if (ov > bv || (ov == bv && oi < idx)) { bv = ov; idx = oi; }
      }
      if (idx == lane) v = -INFINITY;
      if (lane == 0) {
        atomicOr(&bits[r][idx >> 5], 1u << (idx & 31));
        atomicOr(&bits[idx][r >> 5], 1u << (r & 31));
      }
    }
  }
  __syncthreads();
  if (t < D_) {
    uint64_t m = ((uint64_t)bits[t][1] << 32) | (uint64_t)bits[t][0];
    Ads[t] = m;
    Adb[b * D_ + t] = m;
    dinvA[b * D_ + t] = rsqrtf((float)(pop64(m) + 1));
  }
  __syncthreads();
  if (t < D_) {
    uint64_t r1 = Ads[t] | (1ull << t);     // 1 hop (incl. self)
    uint64_t r2 = r1, m = r1;
    while (m) { int j = ctz64(m); m &= m - 1; r2 |= Ads[j]; }  // 2 hops
    Rb[b * D_ + t] = r2;
  }
}

// ---------------------------------------------------------------- stage 3
// Y partials: per (b, kchunk): [64][128] partial of feat2 @ W_sub
__global__ __launch_bounds__(256) void k_Yp(const float* __restrict__ h,
                                            const float* __restrict__ pe_dim,
                                            const float* __restrict__ W_sub,
                                            float* __restrict__ Yp) {
  int b = blockIdx.x, s = blockIdx.y;
  int k0 = s * YCH, kend = k0 + YCH; if (kend > F2) kend = F2;
  __shared__ float Ft[D_][33];
  __shared__ float Wt[32][D2];
  int t = threadIdx.x, tx = t & 15, ty = t >> 4;
  float acc[4][8] = {};
  for (int kt = k0; kt < kend; kt += 32) {
    for (int i = t; i < D_ * 32; i += 256) {
      int kk = i & 31, dd = i >> 5, k = kt + kk;
      float v = 0.f;
      if (k < kend)
        v = (k < ND1) ? h[(((size_t)b * D_ + dd) * N_ + (k >> 6)) * D1 + (k & 63)]
                      : pe_dim[dd * PE2 + (k - ND1)];
      Ft[dd][kk] = v;
    }
    for (int i = t; i < 32 * D2; i += 256) {
      int g = i & 127, kk = i >> 7, k = kt + kk;
      Wt[kk][g] = (k < kend) ? W_sub[(size_t)k * D2 + g] : 0.f;
    }
    __syncthreads();
    for (int kk = 0; kk < 32; ++kk) {
      float a[4], bb[8];
      #pragma unroll
      for (int r = 0; r < 4; ++r) a[r] = Ft[ty * 4 + r][kk];
      #pragma unroll
      for (int c = 0; c < 8; ++c) bb[c] = Wt[kk][tx * 8 + c];
      #pragma unroll
      for (int r = 0; r < 4; ++r)
        #pragma unroll
        for (int c = 0; c < 8; ++c) acc[r][c] += a[r] * bb[c];
    }
    __syncthreads();
  }
  float* out = Yp + (size_t)(b * KSY + s) * D_ * D2;
  for (int r = 0; r < 4; ++r)
    for (int c = 0; c < 8; ++c)
      out[(ty * 4 + r) * D2 + tx * 8 + c] = acc[r][c];
}

__global__ __launch_bounds__(256) void k_Yred(const float* __restrict__ Yp,
                                              float* __restrict__ Y) {
  int i = blockIdx.x * 256 + threadIdx.x;    // over B*64*128
  int b = i >> 13, r = i & 8191;
  float acc = 0.f;
  for (int s = 0; s < KSY; ++s) acc += Yp[(size_t)(b * KSY + s) * 8192 + r];
  Y[i] = acc;
}

// per-center-node subgraph GCN + max pool.  block = (b, center i), 128 thr = f
__global__ __launch_bounds__(128) void k_pool(const float* __restrict__ Y,
                                              const uint64_t* __restrict__ Adb,
                                              const uint64_t* __restrict__ Rb,
                                              const float* __restrict__ b_sub,
                                              float* __restrict__ pooled) {
  int blk = blockIdx.x, b = blk >> 6, i = blk & 63;
  __shared__ float Ys[D_][D2];
  __shared__ float dv[D_];
  __shared__ uint64_t Ads[D_];
  int t = threadIdx.x;
  uint64_t Ri = Rb[b * D_ + i];
  for (int idx = t; idx < D_ * D2; idx += 128)
    Ys[idx >> 7][idx & 127] = Y[(size_t)b * D_ * D2 + idx];
  if (t < D_) {
    uint64_t aj = Adb[b * D_ + t];
    Ads[t] = aj;
    dv[t] = ((Ri >> t) & 1) ? rsqrtf((float)(1 + pop64(aj & Ri))) : 0.f;
  }
  __syncthreads();
  int f = t;
  float best = -INFINITY;
  uint64_t mj = Ri;                  // masks thread-uniform -> no divergence
  while (mj) {
    int j = ctz64(mj); mj &= mj - 1;
    float T = 0.f;
    uint64_t mk = Ads[j] & Ri;
    while (mk) { int k = ctz64(mk); mk &= mk - 1; T += dv[k] * Ys[k][f]; }
    float dj = dv[j];
    float z = dj * T + dj * dj * Ys[j][f] + b_sub[f];
    best = fmaxf(best, z);
  }
  pooled[((size_t)b * D_ + i) * D2 + f] = best;
}

// ---------------------------------------------------------------- stage 4
// Fused: P2 = pooled@W_dim (in LDS) -> dim-graph GCN -> dimout
__global__ __launch_bounds__(256) void k_dim(const float* __restrict__ pooled,
                                             const float* __restrict__ W_dim,
                                             const uint64_t* __restrict__ Adb,
                                             const float* __restrict__ dinvA,
                                             const float* __restrict__ b_dim,
                                             float* __restrict__ dimout) {
  int b = blockIdx.x;
  __shared__ float Ps[D_ * D2];            // 32 KiB union: pooled, then P2*dinv
  __shared__ float dva[D_];
  __shared__ uint64_t Ads[D_];
  int t = threadIdx.x, tx = t & 15, ty = t >> 4;
  if (t < D_) { dva[t] = dinvA[b * D_ + t]; Ads[t] = Adb[b * D_ + t]; }
  for (int i = t; i < D_ * D2; i += 256)
    Ps[i] = pooled[(size_t)b * D_ * D2 + i];
  __syncthreads();
  float acc[4][8] = {};
  for (int k = 0; k < D2; ++k) {
    float a[4], bb[8];
    #pragma unroll
    for (int c = 0; c < 8; ++c) bb[c] = W_dim[k * D2 + tx * 8 + c];
    #pragma unroll
    for (int r = 0; r < 4; ++r) a[r] = Ps[(ty * 4 + r) * D2 + k];
    #pragma unroll
    for (int r = 0; r < 4; ++r)
      #pragma unroll
      for (int c = 0; c < 8; ++c) acc[r][c] += a[r] * bb[c];
  }
  __syncthreads();
  for (int r = 0; r < 4; ++r) {            // overwrite union with P2*dinv
    float dv = dva[ty * 4 + r];
    #pragma unroll
    for (int c = 0; c < 8; ++c)
      Ps[(ty * 4 + r) * D2 + tx * 8 + c] = acc[r][c] * dv;
  }
  __syncthreads();
  int g = t & 127, rg = t >> 7;
  for (int row = rg; row < D_; row += 2) {   // row uniform per wave
    float a = Ps[row * D2 + g];              // self-loop
    uint64_t m = Ads[row];
    while (m) { int e = ctz64(m); m &= m - 1; a += Ps[e * D2 + g]; }
    dimout[((size_t)b * D_ + row) * D2 + g] = dva[row] * a + b_dim[g];
  }
}

// ---------------------------------------------------------------- heads
__global__ __launch_bounds__(256) void k_dom(const float* __restrict__ dimout,
                                             const float* __restrict__ dm1w,
                                             const float* __restrict__ dm1b,
                                             const float* __restrict__ dm2w,
                                             const float* __restrict__ dm2b,
                                             float* __restrict__ dom) {
  __shared__ float vrow[4][D2];
  __shared__ float hid[4][D2];
  int t = threadIdx.x, lane = t & 63, wave = t >> 6;
  int row = blockIdx.x * 4 + wave;
  const float* v = dimout + (size_t)row * D2;
  for (int i = lane; i < D2; i += 64) vrow[wave][i] = v[i];
  __syncthreads();
  for (int u = lane; u < D2; u += 64) {
    float a = dm1b[u];
    for (int k = 0; k < D2; ++k) a += vrow[wave][k] * dm1w[k * D2 + u];
    hid[wave][u] = fmaxf(a, 0.f);
  }
  __syncthreads();
  float a = dm2b[lane];
  for (int k = 0; k < D2; ++k) a += hid[wave][k] * dm2w[k * D_ + lane];
  dom[(size_t)row * D_ + lane] = a;
}

__global__ __launch_bounds__(128) void k_task(const float* __restrict__ dimout,
                                              const float* __restrict__ c1w,
                                              const float* __restrict__ c1b,
                                              const float* __restrict__ c2w,
                                              const float* __restrict__ c2b,
                                              float* __restrict__ task,
                                              float* __restrict__ g_pool) {
  int b = blockIdx.x, f = threadIdx.x;
  __shared__ float gp[D2], hid[D2];
  float m = -INFINITY;
  for (int d = 0; d < D_; ++d)
    m = fmaxf(m, dimout[((size_t)b * D_ + d) * D2 + f]);
  gp[f] = m;
  g_pool[b * D2 + f] = m;
  __syncthreads();
  float a = c1b[f];
  for (int k = 0; k < D2; ++k) a += gp[k] * c1w[k * D2 + f];
  hid[f] = fmaxf(a, 0.f);
  __syncthreads();
  if (f < NC_) {
    float o = c2b[f];
    for (int k = 0; k < D2; ++k) o += hid[k] * c2w[k * NC_ + f];
    task[b * NC_ + f] = o;
  }
}

// ---------------------------------------------------------------- launch
extern "C" void kernel_launch(void* const* d_in, const int* in_sizes, int n_in,
                              void* d_out, int out_size, void* d_ws, size_t ws_size,
                              hipStream_t stream) {
  const float* x        = (const float*)d_in[0];
  const float* pe_inter = (const float*)d_in[1];
  const float* pe_dim   = (const float*)d_in[2];
  const float* W_time   = (const float*)d_in[3];
  const float* b_time   = (const float*)d_in[4];
  const float* W_sub    = (const float*)d_in[5];
  const float* b_sub    = (const float*)d_in[6];
  const float* W_dim    = (const float*)d_in[7];
  const float* b_dim    = (const float*)d_in[8];
  const float* c1w      = (const float*)d_in[9];
  const float* c1b      = (const float*)d_in[10];
  const float* c2w      = (const float*)d_in[11];
  const float* c2b      = (const float*)d_in[12];
  const float* dm1w     = (const float*)d_in[13];
  const float* dm1b     = (const float*)d_in[14];
  const float* dm2w     = (const float*)d_in[15];
  const float* dm2b     = (const float*)d_in[16];

  float* out     = (float*)d_out;
  float* task_o  = out;                       // [16,2]
  float* dom_o   = out + B_ * NC_;            // [1024,64]
  float* gpool_o = out + B_ * NC_ + NP * D_;  // [16,128]

  char* w = (char*)d_ws;
  size_t o = 0;
  auto alloc = [&](size_t bytes) { void* p = w + o; o += (bytes + 255) & ~(size_t)255; return p; };

  float*    hbuf  = (float*)alloc((size_t)NP * N_ * D1 * 4);       // 32 MiB
  uint32_t* bits1 = (uint32_t*)alloc((size_t)NP * 512 * 4);        // 2 MiB
  float*    dinv1 = (float*)alloc((size_t)NP * N_ * 4);
  float*    S2p   = (float*)alloc((size_t)B_ * KS2 * D_ * D_ * 4); // 8 MiB
  uint64_t* Adb   = (uint64_t*)alloc((size_t)B_ * D_ * 8);
  uint64_t* Rb    = (uint64_t*)alloc((size_t)B_ * D_ * 8);
  float*    dinvA = (float*)alloc((size_t)B_ * D_ * 4);
  float*    Yp    = (float*)alloc((size_t)B_ * KSY * D_ * D2 * 4); // 16 MiB
  float*    Y     = (float*)alloc((size_t)B_ * D_ * D2 * 4);
  float*    pooled= (float*)alloc((size_t)B_ * D_ * D2 * 4);
  float*    dimout= (float*)alloc((size_t)B_ * D_ * D2 * 4);
  (void)ws_size; (void)in_sizes; (void)n_in; (void)out_size;

  k_S_topk <<<NP, 256, 0, stream>>>(x, bits1, dinv1);
  k_G_h    <<<NP, 256, 0, stream>>>(x, pe_inter, W_time, bits1, dinv1, b_time, hbuf);
  dim3 g5(B_, KS2);
  k_S2p    <<<g5, 256, 0, stream>>>(hbuf, pe_dim, S2p);
  k_dimgraph<<<B_, 256, 0, stream>>>(S2p, Adb, Rb, dinvA);
  dim3 g8(B_, KSY);
  k_Yp     <<<g8, 256, 0, stream>>>(hbuf, pe_dim, W_sub, Yp);
  k_Yred   <<<(B_ * D_ * D2) / 256, 256, 0, stream>>>(Yp, Y);
  k_pool   <<<B_ * D_, 128, 0, stream>>>(Y, Adb, Rb, b_sub, pooled);
  k_dim    <<<B_, 256, 0, stream>>>(pooled, W_dim, Adb, dinvA, b_dim, dimout);
  k_dom    <<<NP / 4, 256, 0, stream>>>(dimout, dm1w, dm1b, dm2w, dm2b, dom_o);
  k_task   <<<B_, 128, 0, stream>>>(dimout, c1w, c1b, c2w, c2b, task_o, gpool_o);
}

// Round 6
// 751.609 us; speedup vs baseline: 1.2529x; 1.2529x over previous
//
#include <hip/hip_runtime.h>
#include <stdint.h>

namespace {
constexpr int B_ = 16, D_ = 64, N_ = 128, L_ = 256;
constexpr int PE1 = 32, F1 = L_ + PE1;     // 288
constexpr int D1 = 64;
constexpr int ND1 = N_ * D1;               // 8192
constexpr int PE2 = 16, F2 = ND1 + PE2;    // 8208
constexpr int D2 = 128;
constexpr int NC_ = 2;
constexpr int TOPK1 = 8, TOPK2 = 4;
constexpr int NP = B_ * D_;                // 1024 (b,d) pairs
constexpr int KS2 = 32, S2CH = 257;        // ceil(8208/32)
constexpr int KSY = 32, YCH = 257;
}

__device__ __forceinline__ int ctz32(unsigned int m) { return __builtin_ctz(m); }
__device__ __forceinline__ int ctz64(uint64_t m) { return __builtin_ctzll(m); }
__device__ __forceinline__ int pop64(uint64_t m) { return __builtin_popcountll(m); }

// ---------------------------------------------------------------- stage 1
// S = X@X^T with top-8 done DIRECTLY on the accumulator registers:
// row ty*8+r lives in the 16 consecutive lanes sharing ty (8 cols each).
// LDS = staging (16.5 KiB) + bits (2 KiB) only -> ~5 blocks/CU (was 2).
__global__ __launch_bounds__(256) void k_S_topk(const float* __restrict__ x,
                                                uint32_t* __restrict__ bits1,
                                                float* __restrict__ dinv1) {
  int p = blockIdx.x;
  const float* X = x + (size_t)p * N_ * L_;
  __shared__ float Xt[32 * 132];           // [kk][n], 132 pad: 16B rows
  __shared__ unsigned int bits[N_][4];
  int t = threadIdx.x, tx = t & 15, ty = t >> 4;
  for (int i = t; i < N_ * 4; i += 256) ((unsigned int*)bits)[i] = 0u;
  float acc[8][8] = {};
  for (int k0 = 0; k0 < L_; k0 += 32) {
    __syncthreads();                       // prev-iter reads done (also orders bits-zeroing)
    for (int i = t; i < N_ * 32; i += 256) {
      int kk = i & 31, n = i >> 5;
      Xt[kk * 132 + n] = X[n * L_ + k0 + kk];
    }
    __syncthreads();
    for (int kk = 0; kk < 32; ++kk) {
      float a[8], bb[8];
      #pragma unroll
      for (int r = 0; r < 8; ++r) a[r] = Xt[kk * 132 + ty * 8 + r];
      #pragma unroll
      for (int c = 0; c < 8; ++c) bb[c] = Xt[kk * 132 + tx * 8 + c];
      #pragma unroll
      for (int r = 0; r < 8; ++r)
        #pragma unroll
        for (int c = 0; c < 8; ++c) acc[r][c] += a[r] * bb[c];
    }
  }
  // mask diagonal: col tx*8+c == row ty*8+r  <=>  tx==ty && c==r
  if (tx == ty) {
    #pragma unroll
    for (int r = 0; r < 8; ++r) acc[r][r] = -INFINITY;
  }
  // per-row top-8 within each 16-lane group (jax tie-break: larger v, smaller idx)
  #pragma unroll
  for (int r = 0; r < 8; ++r) {
    int row = ty * 8 + r;
    for (int it = 0; it < TOPK1; ++it) {
      float bv = acc[r][0]; int bc = 0;
      #pragma unroll
      for (int c = 1; c < 8; ++c)
        if (acc[r][c] > bv) { bv = acc[r][c]; bc = c; }   // strict > keeps smaller c
      int bidx = tx * 8 + bc;
      #pragma unroll
      for (int off = 1; off < 16; off <<= 1) {
        float ov = __shfl_xor(bv, off);
        int   oi = __shfl_xor(bidx, off);
        if (ov > bv || (ov == bv && oi < bidx)) { bv = ov; bidx = oi; }
      }
      // mask winner by index compare (no dynamic register indexing)
      #pragma unroll
      for (int c = 0; c < 8; ++c)
        if (tx * 8 + c == bidx) acc[r][c] = -INFINITY;
      if (tx == 0) {
        atomicOr(&bits[row][bidx >> 5], 1u << (bidx & 31));
        atomicOr(&bits[bidx][row >> 5], 1u << (row & 31));  // symmetrize
      }
    }
  }
  __syncthreads();
  if (t < N_) {
    int deg = 1;
    for (int w = 0; w < 4; ++w) deg += __popc(bits[t][w]);
    dinv1[(size_t)p * N_ + t] = rsqrtf((float)deg);
  }
  for (int i = t; i < N_ * 4; i += 256)
    bits1[(size_t)p * 512 + i] = ((unsigned int*)bits)[i];
}

// G = concat(x,pe)@W_time[d], pre-scaled by dinv_row, written to global.
// LDS 25.6 KiB -> 6 blocks/CU (split from old fused k_G_h for occupancy).
__global__ __launch_bounds__(256) void k_G(const float* __restrict__ x,
                                           const float* __restrict__ pe_inter,
                                           const float* __restrict__ W_time,
                                           const float* __restrict__ dinv1,
                                           float* __restrict__ G) {
  int p = blockIdx.x, d = p & 63;
  const float* X = x + (size_t)p * N_ * L_;
  const float* W = W_time + (size_t)d * F1 * D1;
  __shared__ float Ft[32 * 132];
  __shared__ float Wt[32 * 64];
  __shared__ float dvs[N_];
  int t = threadIdx.x, tx = t & 15, ty = t >> 4;
  if (t < N_) dvs[t] = dinv1[(size_t)p * N_ + t];
  float acc[8][4] = {};
  for (int k0 = 0; k0 < F1; k0 += 32) {
    __syncthreads();
    for (int i = t; i < N_ * 32; i += 256) {
      int kk = i & 31, n = i >> 5, k = k0 + kk;
      Ft[kk * 132 + n] = (k < L_) ? X[n * L_ + k] : pe_inter[n * PE1 + (k - L_)];
    }
    for (int i = t; i < 32 * D1; i += 256) {
      int f = i & 63, kk = i >> 6;
      Wt[kk * 64 + f] = W[(k0 + kk) * D1 + f];
    }
    __syncthreads();
    for (int kk = 0; kk < 32; ++kk) {
      float a[8], bb[4];
      #pragma unroll
      for (int r = 0; r < 8; ++r) a[r] = Ft[kk * 132 + ty * 8 + r];
      #pragma unroll
      for (int c = 0; c < 4; ++c) bb[c] = Wt[kk * 64 + tx * 4 + c];
      #pragma unroll
      for (int r = 0; r < 8; ++r)
        #pragma unroll
        for (int c = 0; c < 4; ++c) acc[r][c] += a[r] * bb[c];
    }
  }
  float* Gp = G + (size_t)p * N_ * D1;
  for (int r = 0; r < 8; ++r) {
    float dv = dvs[ty * 8 + r];
    #pragma unroll
    for (int c = 0; c < 4; ++c)
      Gp[(ty * 8 + r) * D1 + tx * 4 + c] = acc[r][c] * dv;
  }
}

// h = dinv_i * (Gs_i + sum_{j in A_i} Gs_j) + b_time[d]  (Gs pre-scaled)
__global__ __launch_bounds__(256) void k_h(const float* __restrict__ G,
                                           const uint32_t* __restrict__ bits1,
                                           const float* __restrict__ dinv1,
                                           const float* __restrict__ b_time,
                                           float* __restrict__ h) {
  int p = blockIdx.x, d = p & 63;
  __shared__ float Gs[N_ * D1];            // 32 KiB
  __shared__ unsigned int bs[N_][4];
  __shared__ float dvs[N_];
  int t = threadIdx.x;
  if (t < N_) dvs[t] = dinv1[(size_t)p * N_ + t];
  for (int i = t; i < N_ * 4; i += 256)
    ((unsigned int*)bs)[i] = bits1[(size_t)p * 512 + i];
  for (int i = t; i < N_ * D1; i += 256) Gs[i] = G[(size_t)p * N_ * D1 + i];
  __syncthreads();
  int f = t & 63, wg = t >> 6;
  const float* bt = b_time + d * D1;
  float* hp = h + (size_t)p * N_ * D1;
  for (int row = wg; row < N_; row += 4) {       // row uniform per wave
    float a = Gs[row * D1 + f];                  // self-loop term
    #pragma unroll
    for (int w = 0; w < 4; ++w) {
      unsigned int m = bs[row][w];
      while (m) { int j = (w << 5) + ctz32(m); m &= m - 1; a += Gs[j * D1 + f]; }
    }
    hp[row * D1 + f] = dvs[row] * a + bt[f];
  }
}

// ---------------------------------------------------------------- stage 2
// S2 partials: per (b, kchunk): [64][64] partial of feat2@feat2^T
__global__ __launch_bounds__(256) void k_S2p(const float* __restrict__ h,
                                             const float* __restrict__ pe_dim,
                                             float* __restrict__ S2p) {
  int b = blockIdx.x, s = blockIdx.y;
  int k0 = s * S2CH, kend = k0 + S2CH; if (kend > F2) kend = F2;
  __shared__ float Ft[D_][33];
  int t = threadIdx.x, tx = t & 15, ty = t >> 4;
  float acc[4][4] = {};
  for (int kt = k0; kt < kend; kt += 32) {
    for (int i = t; i < D_ * 32; i += 256) {
      int kk = i & 31, dd = i >> 5, k = kt + kk;
      float v = 0.f;
      if (k < kend)
        v = (k < ND1) ? h[(((size_t)b * D_ + dd) * N_ + (k >> 6)) * D1 + (k & 63)]
                      : pe_dim[dd * PE2 + (k - ND1)];
      Ft[dd][kk] = v;
    }
    __syncthreads();
    for (int kk = 0; kk < 32; ++kk) {
      float a[4], bb[4];
      #pragma unroll
      for (int r = 0; r < 4; ++r) a[r] = Ft[ty * 4 + r][kk];
      #pragma unroll
      for (int c = 0; c < 4; ++c) bb[c] = Ft[tx * 4 + c][kk];
      #pragma unroll
      for (int r = 0; r < 4; ++r)
        #pragma unroll
        for (int c = 0; c < 4; ++c) acc[r][c] += a[r] * bb[c];
    }
    __syncthreads();
  }
  float* out = S2p + (size_t)(b * KS2 + s) * D_ * D_;
  for (int r = 0; r < 4; ++r)
    for (int c = 0; c < 4; ++c)
      out[(ty * 4 + r) * D_ + tx * 4 + c] = acc[r][c];
}

// reduce S2 partials -> top-4 -> symmetrize -> 2-hop reach -> dim dinv
__global__ __launch_bounds__(256) void k_dimgraph(const float* __restrict__ S2p,
                                                  uint64_t* __restrict__ Adb,
                                                  uint64_t* __restrict__ Rb,
                                                  float* __restrict__ dinvA) {
  int b = blockIdx.x;
  __shared__ float S2s[D_][D_ + 1];
  __shared__ unsigned int bits[D_][2];
  __shared__ uint64_t Ads[D_];
  int t = threadIdx.x, lane = t & 63, wave = t >> 6;
  for (int i = t; i < D_ * D_; i += 256) {
    float acc = 0.f;
    for (int s = 0; s < KS2; ++s) acc += S2p[(size_t)(b * KS2 + s) * D_ * D_ + i];
    S2s[i >> 6][i & 63] = acc;
  }
  if (t < D_ * 2) ((unsigned int*)bits)[t] = 0u;
  __syncthreads();
  for (int r = wave; r < D_; r += 4) {
    float v = S2s[r][lane];
    if (lane == r) v = -INFINITY;
    for (int it = 0; it < TOPK2; ++it) {
      float bv = v; int idx = lane;
      for (int off = 32; off; off >>= 1) {
        float ov = __shfl_xor(bv, off);
        int   oi = __shfl_xor(idx, off);
        if (ov > bv || (ov == bv && oi < idx)) { bv = ov; idx = oi; }
      }
      if (idx == lane) v = -INFINITY;
      if (lane == 0) {
        atomicOr(&bits[r][idx >> 5], 1u << (idx & 31));
        atomicOr(&bits[idx][r >> 5], 1u << (r & 31));
      }
    }
  }
  __syncthreads();
  if (t < D_) {
    uint64_t m = ((uint64_t)bits[t][1] << 32) | (uint64_t)bits[t][0];
    Ads[t] = m;
    Adb[b * D_ + t] = m;
    dinvA[b * D_ + t] = rsqrtf((float)(pop64(m) + 1));
  }
  __syncthreads();
  if (t < D_) {
    uint64_t r1 = Ads[t] | (1ull << t);     // 1 hop (incl. self)
    uint64_t r2 = r1, m = r1;
    while (m) { int j = ctz64(m); m &= m - 1; r2 |= Ads[j]; }  // 2 hops
    Rb[b * D_ + t] = r2;
  }
}

// ---------------------------------------------------------------- stage 3
// Y partials: per (b, kchunk): [64][128] partial of feat2 @ W_sub
__global__ __launch_bounds__(256) void k_Yp(const float* __restrict__ h,
                                            const float* __restrict__ pe_dim,
                                            const float* __restrict__ W_sub,
                                            float* __restrict__ Yp) {
  int b = blockIdx.x, s = blockIdx.y;
  int k0 = s * YCH, kend = k0 + YCH; if (kend > F2) kend = F2;
  __shared__ float Ft[D_][33];
  __shared__ float Wt[32][D2];
  int t = threadIdx.x, tx = t & 15, ty = t >> 4;
  float acc[4][8] = {};
  for (int kt = k0; kt < kend; kt += 32) {
    for (int i = t; i < D_ * 32; i += 256) {
      int kk = i & 31, dd = i >> 5, k = kt + kk;
      float v = 0.f;
      if (k < kend)
        v = (k < ND1) ? h[(((size_t)b * D_ + dd) * N_ + (k >> 6)) * D1 + (k & 63)]
                      : pe_dim[dd * PE2 + (k - ND1)];
      Ft[dd][kk] = v;
    }
    for (int i = t; i < 32 * D2; i += 256) {
      int g = i & 127, kk = i >> 7, k = kt + kk;
      Wt[kk][g] = (k < kend) ? W_sub[(size_t)k * D2 + g] : 0.f;
    }
    __syncthreads();
    for (int kk = 0; kk < 32; ++kk) {
      float a[4], bb[8];
      #pragma unroll
      for (int r = 0; r < 4; ++r) a[r] = Ft[ty * 4 + r][kk];
      #pragma unroll
      for (int c = 0; c < 8; ++c) bb[c] = Wt[kk][tx * 8 + c];
      #pragma unroll
      for (int r = 0; r < 4; ++r)
        #pragma unroll
        for (int c = 0; c < 8; ++c) acc[r][c] += a[r] * bb[c];
    }
    __syncthreads();
  }
  float* out = Yp + (size_t)(b * KSY + s) * D_ * D2;
  for (int r = 0; r < 4; ++r)
    for (int c = 0; c < 8; ++c)
      out[(ty * 4 + r) * D2 + tx * 8 + c] = acc[r][c];
}

__global__ __launch_bounds__(256) void k_Yred(const float* __restrict__ Yp,
                                              float* __restrict__ Y) {
  int i = blockIdx.x * 256 + threadIdx.x;    // over B*64*128
  int b = i >> 13, r = i & 8191;
  float acc = 0.f;
  for (int s = 0; s < KSY; ++s) acc += Yp[(size_t)(b * KSY + s) * 8192 + r];
  Y[i] = acc;
}

// per-center-node subgraph GCN + max pool.  block = (b, center i), 128 thr = f
__global__ __launch_bounds__(128) void k_pool(const float* __restrict__ Y,
                                              const uint64_t* __restrict__ Adb,
                                              const uint64_t* __restrict__ Rb,
                                              const float* __restrict__ b_sub,
                                              float* __restrict__ pooled) {
  int blk = blockIdx.x, b = blk >> 6, i = blk & 63;
  __shared__ float Ys[D_][D2];
  __shared__ float dv[D_];
  __shared__ uint64_t Ads[D_];
  int t = threadIdx.x;
  uint64_t Ri = Rb[b * D_ + i];
  for (int idx = t; idx < D_ * D2; idx += 128)
    Ys[idx >> 7][idx & 127] = Y[(size_t)b * D_ * D2 + idx];
  if (t < D_) {
    uint64_t aj = Adb[b * D_ + t];
    Ads[t] = aj;
    dv[t] = ((Ri >> t) & 1) ? rsqrtf((float)(1 + pop64(aj & Ri))) : 0.f;
  }
  __syncthreads();
  int f = t;
  float best = -INFINITY;
  uint64_t mj = Ri;                  // masks thread-uniform -> no divergence
  while (mj) {
    int j = ctz64(mj); mj &= mj - 1;
    float T = 0.f;
    uint64_t mk = Ads[j] & Ri;
    while (mk) { int k = ctz64(mk); mk &= mk - 1; T += dv[k] * Ys[k][f]; }
    float dj = dv[j];
    float z = dj * T + dj * dj * Ys[j][f] + b_sub[f];
    best = fmaxf(best, z);
  }
  pooled[((size_t)b * D_ + i) * D2 + f] = best;
}

// ---------------------------------------------------------------- stage 4
// Fused: P2 = pooled@W_dim (in LDS) -> dim-graph GCN -> dimout
__global__ __launch_bounds__(256) void k_dim(const float* __restrict__ pooled,
                                             const float* __restrict__ W_dim,
                                             const uint64_t* __restrict__ Adb,
                                             const float* __restrict__ dinvA,
                                             const float* __restrict__ b_dim,
                                             float* __restrict__ dimout) {
  int b = blockIdx.x;
  __shared__ float Ps[D_ * D2];            // 32 KiB union: pooled, then P2*dinv
  __shared__ float dva[D_];
  __shared__ uint64_t Ads[D_];
  int t = threadIdx.x, tx = t & 15, ty = t >> 4;
  if (t < D_) { dva[t] = dinvA[b * D_ + t]; Ads[t] = Adb[b * D_ + t]; }
  for (int i = t; i < D_ * D2; i += 256)
    Ps[i] = pooled[(size_t)b * D_ * D2 + i];
  __syncthreads();
  float acc[4][8] = {};
  for (int k = 0; k < D2; ++k) {
    float a[4], bb[8];
    #pragma unroll
    for (int c = 0; c < 8; ++c) bb[c] = W_dim[k * D2 + tx * 8 + c];
    #pragma unroll
    for (int r = 0; r < 4; ++r) a[r] = Ps[(ty * 4 + r) * D2 + k];
    #pragma unroll
    for (int r = 0; r < 4; ++r)
      #pragma unroll
      for (int c = 0; c < 8; ++c) acc[r][c] += a[r] * bb[c];
  }
  __syncthreads();
  for (int r = 0; r < 4; ++r) {            // overwrite union with P2*dinv
    float dv = dva[ty * 4 + r];
    #pragma unroll
    for (int c = 0; c < 8; ++c)
      Ps[(ty * 4 + r) * D2 + tx * 8 + c] = acc[r][c] * dv;
  }
  __syncthreads();
  int g = t & 127, rg = t >> 7;
  for (int row = rg; row < D_; row += 2) {   // row uniform per wave
    float a = Ps[row * D2 + g];              // self-loop
    uint64_t m = Ads[row];
    while (m) { int e = ctz64(m); m &= m - 1; a += Ps[e * D2 + g]; }
    dimout[((size_t)b * D_ + row) * D2 + g] = dva[row] * a + b_dim[g];
  }
}

// ---------------------------------------------------------------- heads
__global__ __launch_bounds__(256) void k_dom(const float* __restrict__ dimout,
                                             const float* __restrict__ dm1w,
                                             const float* __restrict__ dm1b,
                                             const float* __restrict__ dm2w,
                                             const float* __restrict__ dm2b,
                                             float* __restrict__ dom) {
  __shared__ float vrow[4][D2];
  __shared__ float hid[4][D2];
  int t = threadIdx.x, lane = t & 63, wave = t >> 6;
  int row = blockIdx.x * 4 + wave;
  const float* v = dimout + (size_t)row * D2;
  for (int i = lane; i < D2; i += 64) vrow[wave][i] = v[i];
  __syncthreads();
  for (int u = lane; u < D2; u += 64) {
    float a = dm1b[u];
    for (int k = 0; k < D2; ++k) a += vrow[wave][k] * dm1w[k * D2 + u];
    hid[wave][u] = fmaxf(a, 0.f);
  }
  __syncthreads();
  float a = dm2b[lane];
  for (int k = 0; k < D2; ++k) a += hid[wave][k] * dm2w[k * D_ + lane];
  dom[(size_t)row * D_ + lane] = a;
}

__global__ __launch_bounds__(128) void k_task(const float* __restrict__ dimout,
                                              const float* __restrict__ c1w,
                                              const float* __restrict__ c1b,
                                              const float* __restrict__ c2w,
                                              const float* __restrict__ c2b,
                                              float* __restrict__ task,
                                              float* __restrict__ g_pool) {
  int b = blockIdx.x, f = threadIdx.x;
  __shared__ float gp[D2], hid[D2];
  float m = -INFINITY;
  for (int d = 0; d < D_; ++d)
    m = fmaxf(m, dimout[((size_t)b * D_ + d) * D2 + f]);
  gp[f] = m;
  g_pool[b * D2 + f] = m;
  __syncthreads();
  float a = c1b[f];
  for (int k = 0; k < D2; ++k) a += gp[k] * c1w[k * D2 + f];
  hid[f] = fmaxf(a, 0.f);
  __syncthreads();
  if (f < NC_) {
    float o = c2b[f];
    for (int k = 0; k < D2; ++k) o += hid[k] * c2w[k * NC_ + f];
    task[b * NC_ + f] = o;
  }
}

// ---------------------------------------------------------------- launch
extern "C" void kernel_launch(void* const* d_in, const int* in_sizes, int n_in,
                              void* d_out, int out_size, void* d_ws, size_t ws_size,
                              hipStream_t stream) {
  const float* x        = (const float*)d_in[0];
  const float* pe_inter = (const float*)d_in[1];
  const float* pe_dim   = (const float*)d_in[2];
  const float* W_time   = (const float*)d_in[3];
  const float* b_time   = (const float*)d_in[4];
  const float* W_sub    = (const float*)d_in[5];
  const float* b_sub    = (const float*)d_in[6];
  const float* W_dim    = (const float*)d_in[7];
  const float* b_dim    = (const float*)d_in[8];
  const float* c1w      = (const float*)d_in[9];
  const float* c1b      = (const float*)d_in[10];
  const float* c2w      = (const float*)d_in[11];
  const float* c2b      = (const float*)d_in[12];
  const float* dm1w     = (const float*)d_in[13];
  const float* dm1b     = (const float*)d_in[14];
  const float* dm2w     = (const float*)d_in[15];
  const float* dm2b     = (const float*)d_in[16];

  float* out     = (float*)d_out;
  float* task_o  = out;                       // [16,2]
  float* dom_o   = out + B_ * NC_;            // [1024,64]
  float* gpool_o = out + B_ * NC_ + NP * D_;  // [16,128]

  char* w = (char*)d_ws;
  size_t o = 0;
  auto alloc = [&](size_t bytes) { void* p = w + o; o += (bytes + 255) & ~(size_t)255; return p; };

  float*    hbuf  = (float*)alloc((size_t)NP * N_ * D1 * 4);       // 32 MiB
  uint32_t* bits1 = (uint32_t*)alloc((size_t)NP * 512 * 4);        // 2 MiB
  float*    dinv1 = (float*)alloc((size_t)NP * N_ * 4);
  float*    S2p   = (float*)alloc((size_t)B_ * KS2 * D_ * D_ * 4); // 8 MiB
  uint64_t* Adb   = (uint64_t*)alloc((size_t)B_ * D_ * 8);
  uint64_t* Rb    = (uint64_t*)alloc((size_t)B_ * D_ * 8);
  float*    dinvA = (float*)alloc((size_t)B_ * D_ * 4);
  float*    Yp    = (float*)alloc((size_t)B_ * KSY * D_ * D2 * 4); // 16 MiB
  float*    Y     = (float*)alloc((size_t)B_ * D_ * D2 * 4);
  float*    pooled= (float*)alloc((size_t)B_ * D_ * D2 * 4);
  float*    dimout= (float*)alloc((size_t)B_ * D_ * D2 * 4);
  (void)ws_size; (void)in_sizes; (void)n_in; (void)out_size;

  // G (32 MiB) aliases [S2p .. pooled): those buffers are written only AFTER
  // k_h has consumed G (stream-ordered), so no growth of ws usage.
  float* Gbuf = S2p;

  k_S_topk <<<NP, 256, 0, stream>>>(x, bits1, dinv1);
  k_G      <<<NP, 256, 0, stream>>>(x, pe_inter, W_time, dinv1, Gbuf);
  k_h      <<<NP, 256, 0, stream>>>(Gbuf, bits1, dinv1, b_time, hbuf);
  dim3 g5(B_, KS2);
  k_S2p    <<<g5, 256, 0, stream>>>(hbuf, pe_dim, S2p);
  k_dimgraph<<<B_, 256, 0, stream>>>(S2p, Adb, Rb, dinvA);
  dim3 g8(B_, KSY);
  k_Yp     <<<g8, 256, 0, stream>>>(hbuf, pe_dim, W_sub, Yp);
  k_Yred   <<<(B_ * D_ * D2) / 256, 256, 0, stream>>>(Yp, Y);
  k_pool   <<<B_ * D_, 128, 0, stream>>>(Y, Adb, Rb, b_sub, pooled);
  k_dim    <<<B_, 256, 0, stream>>>(pooled, W_dim, Adb, dinvA, b_dim, dimout);
  k_dom    <<<NP / 4, 256, 0, stream>>>(dimout, dm1w, dm1b, dm2w, dm2b, dom_o);
  k_task   <<<B_, 128, 0, stream>>>(dimout, c1w, c1b, c2w, c2b, task_o, gpool_o);
}

// Round 7
// 700.024 us; speedup vs baseline: 1.3453x; 1.0737x over previous
//
#include <hip/hip_runtime.h>
#include <stdint.h>

namespace {
constexpr int B_ = 16, D_ = 64, N_ = 128, L_ = 256;
constexpr int PE1 = 32, F1 = L_ + PE1;     // 288
constexpr int D1 = 64;
constexpr int ND1 = N_ * D1;               // 8192
constexpr int PE2 = 16, F2 = ND1 + PE2;    // 8208
constexpr int D2 = 128;
constexpr int NC_ = 2;
constexpr int TOPK1 = 8, TOPK2 = 4;
constexpr int NP = B_ * D_;                // 1024 (b,d) pairs
constexpr int KS2 = 32, S2CH = 257;        // ceil(8208/32)
constexpr int KSY = 32, YCH = 257;
}

__device__ __forceinline__ int ctz32(unsigned int m) { return __builtin_ctz(m); }
__device__ __forceinline__ int ctz64(uint64_t m) { return __builtin_ctzll(m); }
__device__ __forceinline__ int pop64(uint64_t m) { return __builtin_popcountll(m); }

// ---------------------------------------------------------------- stage 1
// S = X@X^T, top-8 on accumulator registers. 512 thr, 4x8 tile/thread:
// acc 32 + operands ~22 VGPR -> <=64 -> 8 waves/SIMD (was 68 VGPR, 2 w/SIMD).
__global__ __launch_bounds__(512, 8) void k_S_topk(const float* __restrict__ x,
                                                   uint32_t* __restrict__ bits1,
                                                   float* __restrict__ dinv1) {
  int p = blockIdx.x;
  const float* X = x + (size_t)p * N_ * L_;
  __shared__ float Xt[32 * 132];           // [kk][n], 132 pad: 16B rows
  __shared__ unsigned int bits[N_][4];
  int t = threadIdx.x, tx = t & 15, ty = t >> 4;   // ty in [0,32): 4 rows each
  if (t < N_ * 4) ((unsigned int*)bits)[t] = 0u;
  float acc[4][8] = {};
  for (int k0 = 0; k0 < L_; k0 += 32) {
    __syncthreads();                       // prev reads done (also orders bits-zeroing)
    for (int i = t; i < N_ * 32; i += 512) {
      int kk = i & 31, n = i >> 5;
      Xt[kk * 132 + n] = X[n * L_ + k0 + kk];
    }
    __syncthreads();
    for (int kk = 0; kk < 32; ++kk) {
      float a[4], bb[8];
      #pragma unroll
      for (int r = 0; r < 4; ++r) a[r] = Xt[kk * 132 + ty * 4 + r];
      #pragma unroll
      for (int c = 0; c < 8; ++c) bb[c] = Xt[kk * 132 + tx * 8 + c];
      #pragma unroll
      for (int r = 0; r < 4; ++r)
        #pragma unroll
        for (int c = 0; c < 8; ++c) acc[r][c] += a[r] * bb[c];
    }
  }
  // mask diagonal: ty*4+r == tx*8+c
  #pragma unroll
  for (int r = 0; r < 4; ++r)
    #pragma unroll
    for (int c = 0; c < 8; ++c)
      if (ty * 4 + r == tx * 8 + c) acc[r][c] = -INFINITY;
  // per-row top-8 within each 16-lane group (jax tie-break: larger v, smaller idx)
  #pragma unroll
  for (int r = 0; r < 4; ++r) {
    int row = ty * 4 + r;
    for (int it = 0; it < TOPK1; ++it) {
      float bv = acc[r][0]; int bc = 0;
      #pragma unroll
      for (int c = 1; c < 8; ++c)
        if (acc[r][c] > bv) { bv = acc[r][c]; bc = c; }   // strict > keeps smaller c
      int bidx = tx * 8 + bc;
      #pragma unroll
      for (int off = 1; off < 16; off <<= 1) {
        float ov = __shfl_xor(bv, off);
        int   oi = __shfl_xor(bidx, off);
        if (ov > bv || (ov == bv && oi < bidx)) { bv = ov; bidx = oi; }
      }
      #pragma unroll
      for (int c = 0; c < 8; ++c)        // mask winner by index compare
        if (tx * 8 + c == bidx) acc[r][c] = -INFINITY;
      if (tx == 0) {
        atomicOr(&bits[row][bidx >> 5], 1u << (bidx & 31));
        atomicOr(&bits[bidx][row >> 5], 1u << (row & 31));  // symmetrize
      }
    }
  }
  __syncthreads();
  if (t < N_) {
    int deg = 1;
    for (int w = 0; w < 4; ++w) deg += __popc(bits[t][w]);
    dinv1[(size_t)p * N_ + t] = rsqrtf((float)deg);
  }
  if (t < N_ * 4)
    bits1[(size_t)p * 512 + t] = ((unsigned int*)bits)[t];
}

// Fused: G = concat(x,pe)@W_time[d] in LDS (pre-scaled by dinv) -> sparse
// GCN gather -> h. 512 thr, 4x4 tile. LDS union{Ft+Wt | Gs[128][64]} = 32 KiB.
__global__ __launch_bounds__(512, 8) void k_G_h(const float* __restrict__ x,
                                                const float* __restrict__ pe_inter,
                                                const float* __restrict__ W_time,
                                                const uint32_t* __restrict__ bits1,
                                                const float* __restrict__ dinv1,
                                                const float* __restrict__ b_time,
                                                float* __restrict__ h) {
  int p = blockIdx.x, d = p & 63;
  const float* X = x + (size_t)p * N_ * L_;
  const float* W = W_time + (size_t)d * F1 * D1;
  __shared__ float smem[N_ * D1];          // 32 KiB union
  __shared__ unsigned int bs[N_][4];
  __shared__ float dvs[N_];
  float* Ft = smem;                        // [32][132] = 4224 floats
  float* Wt = smem + 4224;                 // [32][64]  = 2048 floats
  int t = threadIdx.x, tx = t & 15, ty = t >> 4;   // 4 rows x 4 cols per thread
  if (t < N_) dvs[t] = dinv1[(size_t)p * N_ + t];
  if (t < N_ * 4) ((unsigned int*)bs)[t] = bits1[(size_t)p * 512 + t];
  float acc[4][4] = {};
  for (int k0 = 0; k0 < F1; k0 += 32) {
    __syncthreads();
    for (int i = t; i < N_ * 32; i += 512) {
      int kk = i & 31, n = i >> 5, k = k0 + kk;
      Ft[kk * 132 + n] = (k < L_) ? X[n * L_ + k] : pe_inter[n * PE1 + (k - L_)];
    }
    for (int i = t; i < 32 * D1; i += 512) {
      int f = i & 63, kk = i >> 6;
      Wt[kk * 64 + f] = W[(k0 + kk) * D1 + f];
    }
    __syncthreads();
    for (int kk = 0; kk < 32; ++kk) {
      float a[4], bb[4];
      #pragma unroll
      for (int r = 0; r < 4; ++r) a[r] = Ft[kk * 132 + ty * 4 + r];
      #pragma unroll
      for (int c = 0; c < 4; ++c) bb[c] = Wt[kk * 64 + tx * 4 + c];
      #pragma unroll
      for (int r = 0; r < 4; ++r)
        #pragma unroll
        for (int c = 0; c < 4; ++c) acc[r][c] += a[r] * bb[c];
    }
  }
  __syncthreads();                         // staging reads done -> alias as Gs
  for (int r = 0; r < 4; ++r) {
    float dv = dvs[ty * 4 + r];
    #pragma unroll
    for (int c = 0; c < 4; ++c)
      smem[(ty * 4 + r) * D1 + tx * 4 + c] = acc[r][c] * dv;
  }
  __syncthreads();
  int f = t & 63, wg = t >> 6;             // 8 waves -> 8 row-strides
  const float* bt = b_time + d * D1;
  float* hp = h + (size_t)p * N_ * D1;
  for (int row = wg; row < N_; row += 8) {       // row uniform per wave
    float a = smem[row * D1 + f];                // self-loop term
    #pragma unroll
    for (int w = 0; w < 4; ++w) {
      unsigned int m = bs[row][w];
      while (m) { int j = (w << 5) + ctz32(m); m &= m - 1; a += smem[j * D1 + f]; }
    }
    hp[row * D1 + f] = dvs[row] * a + bt[f];
  }
}

// ---------------------------------------------------------------- stage 2
// S2 partials: per (b, kchunk): [64][64] partial of feat2@feat2^T
__global__ __launch_bounds__(256) void k_S2p(const float* __restrict__ h,
                                             const float* __restrict__ pe_dim,
                                             float* __restrict__ S2p) {
  int b = blockIdx.x, s = blockIdx.y;
  int k0 = s * S2CH, kend = k0 + S2CH; if (kend > F2) kend = F2;
  __shared__ float Ft[D_][33];
  int t = threadIdx.x, tx = t & 15, ty = t >> 4;
  float acc[4][4] = {};
  for (int kt = k0; kt < kend; kt += 32) {
    for (int i = t; i < D_ * 32; i += 256) {
      int kk = i & 31, dd = i >> 5, k = kt + kk;
      float v = 0.f;
      if (k < kend)
        v = (k < ND1) ? h[(((size_t)b * D_ + dd) * N_ + (k >> 6)) * D1 + (k & 63)]
                      : pe_dim[dd * PE2 + (k - ND1)];
      Ft[dd][kk] = v;
    }
    __syncthreads();
    for (int kk = 0; kk < 32; ++kk) {
      float a[4], bb[4];
      #pragma unroll
      for (int r = 0; r < 4; ++r) a[r] = Ft[ty * 4 + r][kk];
      #pragma unroll
      for (int c = 0; c < 4; ++c) bb[c] = Ft[tx * 4 + c][kk];
      #pragma unroll
      for (int r = 0; r < 4; ++r)
        #pragma unroll
        for (int c = 0; c < 4; ++c) acc[r][c] += a[r] * bb[c];
    }
    __syncthreads();
  }
  float* out = S2p + (size_t)(b * KS2 + s) * D_ * D_;
  for (int r = 0; r < 4; ++r)
    for (int c = 0; c < 4; ++c)
      out[(ty * 4 + r) * D_ + tx * 4 + c] = acc[r][c];
}

// reduce S2 partials -> top-4 -> symmetrize -> 2-hop reach -> dim dinv
__global__ __launch_bounds__(256) void k_dimgraph(const float* __restrict__ S2p,
                                                  uint64_t* __restrict__ Adb,
                                                  uint64_t* __restrict__ Rb,
                                                  float* __restrict__ dinvA) {
  int b = blockIdx.x;
  __shared__ float S2s[D_][D_ + 1];
  __shared__ unsigned int bits[D_][2];
  __shared__ uint64_t Ads[D_];
  int t = threadIdx.x, lane = t & 63, wave = t >> 6;
  for (int i = t; i < D_ * D_; i += 256) {
    float acc = 0.f;
    for (int s = 0; s < KS2; ++s) acc += S2p[(size_t)(b * KS2 + s) * D_ * D_ + i];
    S2s[i >> 6][i & 63] = acc;
  }
  if (t < D_ * 2) ((unsigned int*)bits)[t] = 0u;
  __syncthreads();
  for (int r = wave; r < D_; r += 4) {
    float v = S2s[r][lane];
    if (lane == r) v = -INFINITY;
    for (int it = 0; it < TOPK2; ++it) {
      float bv = v; int idx = lane;
      for (int off = 32; off; off >>= 1) {
        float ov = __shfl_xor(bv, off);
        int   oi = __shfl_xor(idx, off);
        if (ov > bv || (ov == bv && oi < idx)) { bv = ov; idx = oi; }
      }
      if (idx == lane) v = -INFINITY;
      if (lane == 0) {
        atomicOr(&bits[r][idx >> 5], 1u << (idx & 31));
        atomicOr(&bits[idx][r >> 5], 1u << (r & 31));
      }
    }
  }
  __syncthreads();
  if (t < D_) {
    uint64_t m = ((uint64_t)bits[t][1] << 32) | (uint64_t)bits[t][0];
    Ads[t] = m;
    Adb[b * D_ + t] = m;
    dinvA[b * D_ + t] = rsqrtf((float)(pop64(m) + 1));
  }
  __syncthreads();
  if (t < D_) {
    uint64_t r1 = Ads[t] | (1ull << t);     // 1 hop (incl. self)
    uint64_t r2 = r1, m = r1;
    while (m) { int j = ctz64(m); m &= m - 1; r2 |= Ads[j]; }  // 2 hops
    Rb[b * D_ + t] = r2;
  }
}

// ---------------------------------------------------------------- stage 3
// Y partials: per (b, kchunk): [64][128] partial of feat2 @ W_sub
__global__ __launch_bounds__(256) void k_Yp(const float* __restrict__ h,
                                            const float* __restrict__ pe_dim,
                                            const float* __restrict__ W_sub,
                                            float* __restrict__ Yp) {
  int b = blockIdx.x, s = blockIdx.y;
  int k0 = s * YCH, kend = k0 + YCH; if (kend > F2) kend = F2;
  __shared__ float Ft[D_][33];
  __shared__ float Wt[32][D2];
  int t = threadIdx.x, tx = t & 15, ty = t >> 4;
  float acc[4][8] = {};
  for (int kt = k0; kt < kend; kt += 32) {
    for (int i = t; i < D_ * 32; i += 256) {
      int kk = i & 31, dd = i >> 5, k = kt + kk;
      float v = 0.f;
      if (k < kend)
        v = (k < ND1) ? h[(((size_t)b * D_ + dd) * N_ + (k >> 6)) * D1 + (k & 63)]
                      : pe_dim[dd * PE2 + (k - ND1)];
      Ft[dd][kk] = v;
    }
    for (int i = t; i < 32 * D2; i += 256) {
      int g = i & 127, kk = i >> 7, k = kt + kk;
      Wt[kk][g] = (k < kend) ? W_sub[(size_t)k * D2 + g] : 0.f;
    }
    __syncthreads();
    for (int kk = 0; kk < 32; ++kk) {
      float a[4], bb[8];
      #pragma unroll
      for (int r = 0; r < 4; ++r) a[r] = Ft[ty * 4 + r][kk];
      #pragma unroll
      for (int c = 0; c < 8; ++c) bb[c] = Wt[kk][tx * 8 + c];
      #pragma unroll
      for (int r = 0; r < 4; ++r)
        #pragma unroll
        for (int c = 0; c < 8; ++c) acc[r][c] += a[r] * bb[c];
    }
    __syncthreads();
  }
  float* out = Yp + (size_t)(b * KSY + s) * D_ * D2;
  for (int r = 0; r < 4; ++r)
    for (int c = 0; c < 8; ++c)
      out[(ty * 4 + r) * D2 + tx * 8 + c] = acc[r][c];
}

__global__ __launch_bounds__(256) void k_Yred(const float* __restrict__ Yp,
                                              float* __restrict__ Y) {
  int i = blockIdx.x * 256 + threadIdx.x;    // over B*64*128
  int b = i >> 13, r = i & 8191;
  float acc = 0.f;
  for (int s = 0; s < KSY; ++s) acc += Yp[(size_t)(b * KSY + s) * 8192 + r];
  Y[i] = acc;
}

// per-center-node subgraph GCN + max pool.  block = (b, center i), 128 thr = f
__global__ __launch_bounds__(128) void k_pool(const float* __restrict__ Y,
                                              const uint64_t* __restrict__ Adb,
                                              const uint64_t* __restrict__ Rb,
                                              const float* __restrict__ b_sub,
                                              float* __restrict__ pooled) {
  int blk = blockIdx.x, b = blk >> 6, i = blk & 63;
  __shared__ float Ys[D_][D2];
  __shared__ float dv[D_];
  __shared__ uint64_t Ads[D_];
  int t = threadIdx.x;
  uint64_t Ri = Rb[b * D_ + i];
  for (int idx = t; idx < D_ * D2; idx += 128)
    Ys[idx >> 7][idx & 127] = Y[(size_t)b * D_ * D2 + idx];
  if (t < D_) {
    uint64_t aj = Adb[b * D_ + t];
    Ads[t] = aj;
    dv[t] = ((Ri >> t) & 1) ? rsqrtf((float)(1 + pop64(aj & Ri))) : 0.f;
  }
  __syncthreads();
  int f = t;
  float best = -INFINITY;
  uint64_t mj = Ri;                  // masks thread-uniform -> no divergence
  while (mj) {
    int j = ctz64(mj); mj &= mj - 1;
    float T = 0.f;
    uint64_t mk = Ads[j] & Ri;
    while (mk) { int k = ctz64(mk); mk &= mk - 1; T += dv[k] * Ys[k][f]; }
    float dj = dv[j];
    float z = dj * T + dj * dj * Ys[j][f] + b_sub[f];
    best = fmaxf(best, z);
  }
  pooled[((size_t)b * D_ + i) * D2 + f] = best;
}

// ---------------------------------------------------------------- stage 4
// Fused: P2 = pooled@W_dim (in LDS) -> dim-graph GCN -> dimout
__global__ __launch_bounds__(256) void k_dim(const float* __restrict__ pooled,
                                             const float* __restrict__ W_dim,
                                             const uint64_t* __restrict__ Adb,
                                             const float* __restrict__ dinvA,
                                             const float* __restrict__ b_dim,
                                             float* __restrict__ dimout) {
  int b = blockIdx.x;
  __shared__ float Ps[D_ * D2];            // 32 KiB union: pooled, then P2*dinv
  __shared__ float dva[D_];
  __shared__ uint64_t Ads[D_];
  int t = threadIdx.x, tx = t & 15, ty = t >> 4;
  if (t < D_) { dva[t] = dinvA[b * D_ + t]; Ads[t] = Adb[b * D_ + t]; }
  for (int i = t; i < D_ * D2; i += 256)
    Ps[i] = pooled[(size_t)b * D_ * D2 + i];
  __syncthreads();
  float acc[4][8] = {};
  for (int k = 0; k < D2; ++k) {
    float a[4], bb[8];
    #pragma unroll
    for (int c = 0; c < 8; ++c) bb[c] = W_dim[k * D2 + tx * 8 + c];
    #pragma unroll
    for (int r = 0; r < 4; ++r) a[r] = Ps[(ty * 4 + r) * D2 + k];
    #pragma unroll
    for (int r = 0; r < 4; ++r)
      #pragma unroll
      for (int c = 0; c < 8; ++c) acc[r][c] += a[r] * bb[c];
  }
  __syncthreads();
  for (int r = 0; r < 4; ++r) {            // overwrite union with P2*dinv
    float dv = dva[ty * 4 + r];
    #pragma unroll
    for (int c = 0; c < 8; ++c)
      Ps[(ty * 4 + r) * D2 + tx * 8 + c] = acc[r][c] * dv;
  }
  __syncthreads();
  int g = t & 127, rg = t >> 7;
  for (int row = rg; row < D_; row += 2) {   // row uniform per wave
    float a = Ps[row * D2 + g];              // self-loop
    uint64_t m = Ads[row];
    while (m) { int e = ctz64(m); m &= m - 1; a += Ps[e * D2 + g]; }
    dimout[((size_t)b * D_ + row) * D2 + g] = dva[row] * a + b_dim[g];
  }
}

// ---------------------------------------------------------------- heads
__global__ __launch_bounds__(256) void k_dom(const float* __restrict__ dimout,
                                             const float* __restrict__ dm1w,
                                             const float* __restrict__ dm1b,
                                             const float* __restrict__ dm2w,
                                             const float* __restrict__ dm2b,
                                             float* __restrict__ dom) {
  __shared__ float vrow[4][D2];
  __shared__ float hid[4][D2];
  int t = threadIdx.x, lane = t & 63, wave = t >> 6;
  int row = blockIdx.x * 4 + wave;
  const float* v = dimout + (size_t)row * D2;
  for (int i = lane; i < D2; i += 64) vrow[wave][i] = v[i];
  __syncthreads();
  for (int u = lane; u < D2; u += 64) {
    float a = dm1b[u];
    for (int k = 0; k < D2; ++k) a += vrow[wave][k] * dm1w[k * D2 + u];
    hid[wave][u] = fmaxf(a, 0.f);
  }
  __syncthreads();
  float a = dm2b[lane];
  for (int k = 0; k < D2; ++k) a += hid[wave][k] * dm2w[k * D_ + lane];
  dom[(size_t)row * D_ + lane] = a;
}

__global__ __launch_bounds__(128) void k_task(const float* __restrict__ dimout,
                                              const float* __restrict__ c1w,
                                              const float* __restrict__ c1b,
                                              const float* __restrict__ c2w,
                                              const float* __restrict__ c2b,
                                              float* __restrict__ task,
                                              float* __restrict__ g_pool) {
  int b = blockIdx.x, f = threadIdx.x;
  __shared__ float gp[D2], hid[D2];
  float m = -INFINITY;
  for (int d = 0; d < D_; ++d)
    m = fmaxf(m, dimout[((size_t)b * D_ + d) * D2 + f]);
  gp[f] = m;
  g_pool[b * D2 + f] = m;
  __syncthreads();
  float a = c1b[f];
  for (int k = 0; k < D2; ++k) a += gp[k] * c1w[k * D2 + f];
  hid[f] = fmaxf(a, 0.f);
  __syncthreads();
  if (f < NC_) {
    float o = c2b[f];
    for (int k = 0; k < D2; ++k) o += hid[k] * c2w[k * NC_ + f];
    task[b * NC_ + f] = o;
  }
}

// ---------------------------------------------------------------- launch
extern "C" void kernel_launch(void* const* d_in, const int* in_sizes, int n_in,
                              void* d_out, int out_size, void* d_ws, size_t ws_size,
                              hipStream_t stream) {
  const float* x        = (const float*)d_in[0];
  const float* pe_inter = (const float*)d_in[1];
  const float* pe_dim   = (const float*)d_in[2];
  const float* W_time   = (const float*)d_in[3];
  const float* b_time   = (const float*)d_in[4];
  const float* W_sub    = (const float*)d_in[5];
  const float* b_sub    = (const float*)d_in[6];
  const float* W_dim    = (const float*)d_in[7];
  const float* b_dim    = (const float*)d_in[8];
  const float* c1w      = (const float*)d_in[9];
  const float* c1b      = (const float*)d_in[10];
  const float* c2w      = (const float*)d_in[11];
  const float* c2b      = (const float*)d_in[12];
  const float* dm1w     = (const float*)d_in[13];
  const float* dm1b     = (const float*)d_in[14];
  const float* dm2w     = (const float*)d_in[15];
  const float* dm2b     = (const float*)d_in[16];

  float* out     = (float*)d_out;
  float* task_o  = out;                       // [16,2]
  float* dom_o   = out + B_ * NC_;            // [1024,64]
  float* gpool_o = out + B_ * NC_ + NP * D_;  // [16,128]

  char* w = (char*)d_ws;
  size_t o = 0;
  auto alloc = [&](size_t bytes) { void* p = w + o; o += (bytes + 255) & ~(size_t)255; return p; };

  float*    hbuf  = (float*)alloc((size_t)NP * N_ * D1 * 4);       // 32 MiB
  uint32_t* bits1 = (uint32_t*)alloc((size_t)NP * 512 * 4);        // 2 MiB
  float*    dinv1 = (float*)alloc((size_t)NP * N_ * 4);
  float*    S2p   = (float*)alloc((size_t)B_ * KS2 * D_ * D_ * 4); // 8 MiB
  uint64_t* Adb   = (uint64_t*)alloc((size_t)B_ * D_ * 8);
  uint64_t* Rb    = (uint64_t*)alloc((size_t)B_ * D_ * 8);
  float*    dinvA = (float*)alloc((size_t)B_ * D_ * 4);
  float*    Yp    = (float*)alloc((size_t)B_ * KSY * D_ * D2 * 4); // 16 MiB
  float*    Y     = (float*)alloc((size_t)B_ * D_ * D2 * 4);
  float*    pooled= (float*)alloc((size_t)B_ * D_ * D2 * 4);
  float*    dimout= (float*)alloc((size_t)B_ * D_ * D2 * 4);
  (void)ws_size; (void)in_sizes; (void)n_in; (void)out_size;

  k_S_topk <<<NP, 512, 0, stream>>>(x, bits1, dinv1);
  k_G_h    <<<NP, 512, 0, stream>>>(x, pe_inter, W_time, bits1, dinv1, b_time, hbuf);
  dim3 g5(B_, KS2);
  k_S2p    <<<g5, 256, 0, stream>>>(hbuf, pe_dim, S2p);
  k_dimgraph<<<B_, 256, 0, stream>>>(S2p, Adb, Rb, dinvA);
  dim3 g8(B_, KSY);
  k_Yp     <<<g8, 256, 0, stream>>>(hbuf, pe_dim, W_sub, Yp);
  k_Yred   <<<(B_ * D_ * D2) / 256, 256, 0, stream>>>(Yp, Y);
  k_pool   <<<B_ * D_, 128, 0, stream>>>(Y, Adb, Rb, b_sub, pooled);
  k_dim    <<<B_, 256, 0, stream>>>(pooled, W_dim, Adb, dinvA, b_dim, dimout);
  k_dom    <<<NP / 4, 256, 0, stream>>>(dimout, dm1w, dm1b, dm2w, dm2b, dom_o);
  k_task   <<<B_, 128, 0, stream>>>(dimout, c1w, c1b, c2w, c2b, task_o, gpool_o);
}